// Round 1
// baseline (147.592 us; speedup 1.0000x reference)
//
#include <hip/hip_runtime.h>
#include <hip/hip_bf16.h>
#include <cstddef>

// Problem constants (from reference): B=16, N=512, C_SIZE=512, STRIDE=8
// -> C = 64 grid cells per axis, M = C*C = 4096 pixels, output [B, N+1, M] fp32.
constexpr int NPT  = 512;            // points per image
constexpr int C    = 64;             // density-grid side
constexpr int M    = C * C;          // 4096 pixels
constexpr int NP1  = NPT + 1;        // points + background row
constexpr float SIG2INV = 1.0f / 128.0f;   // 1/(2*sigma^2), sigma=8
constexpr float BG_RATIO = 0.15f;
constexpr float EPS = 1e-5f;

// Block = 256 threads = 4 waves, handles one (b, i) row of 64 pixels.
// thread t: j = t & 63 (pixel column), pc = t >> 6 (point-chunk of 128).
// Each pixel's softmax over the 513 "point" axis is computed via a 4-way
// LDS reduction (min, then sum), then pass 3 recomputes exp and streams out.
__global__ __launch_bounds__(256) void pp_kernel(
    const float* __restrict__ points,   // [B, NPT, 2] (x, y)
    const float* __restrict__ st,       // [B]
    float* __restrict__ out)            // [B, NP1, M]
{
    const int b = blockIdx.x >> 6;   // 16 images
    const int i = blockIdx.x & 63;   // grid row
    const int t = threadIdx.x;
    const int j = t & 63;
    const int pc = t >> 6;

    const float cy = (float)(i * 8 + 4);
    const float cx = (float)(j * 8 + 4);

    __shared__ float2 pts[NPT];      // 4 KB: per-image points
    __shared__ float  red[256];      // 4-way reduction scratch
    __shared__ float  qs[C];         // per-pixel max-logit numerator (min(mind,bg))
    __shared__ float  bgs[C];        // per-pixel background distance
    __shared__ float  rs[C];         // per-pixel 1/sum

    // Stage points[b] into LDS (coalesced float2 loads).
    const float2* pb = (const float2*)(points + (size_t)b * NPT * 2);
    for (int p = t; p < NPT; p += 256) pts[p] = pb[p];
    __syncthreads();

    const int p0 = pc * 128, p1 = p0 + 128;

    // ---- Pass 1: min distance over this thread's point chunk ----
    float mind = 3.4e38f;
    #pragma unroll 8
    for (int p = p0; p < p1; ++p) {
        float2 xy = pts[p];                       // wave-broadcast ds_read_b64
        float dy = xy.y - cy;
        float dx = xy.x - cx;
        float d  = fmaf(dx, dx, dy * dy);
        mind = fminf(mind, d);
    }
    red[t] = mind;
    __syncthreads();

    if (t < C) {
        float m0 = fminf(fminf(red[j], red[64 + j]),
                         fminf(red[128 + j], red[192 + j]));
        float s  = st[b] * BG_RATIO;
        float bg = (s * s) / (m0 + EPS);
        qs[j]  = fminf(m0, bg);   // -q/128 is the exact max logit
        bgs[j] = bg;
    }
    __syncthreads();

    const float q  = qs[j];
    const float qk = q * SIG2INV;

    // ---- Pass 2: sum of exp over this thread's chunk ----
    float sum = 0.0f;
    #pragma unroll 8
    for (int p = p0; p < p1; ++p) {
        float2 xy = pts[p];
        float dy = xy.y - cy;
        float dx = xy.x - cx;
        float d  = fmaf(dx, dx, dy * dy);
        sum += __expf(fmaf(-d, SIG2INV, qk));     // arg <= 0 always
    }
    red[t] = sum;
    __syncthreads();

    if (t < C) {
        float s = (red[j] + red[64 + j]) + (red[128 + j] + red[192 + j]);
        s += __expf(fmaf(-bgs[j], SIG2INV, qs[j] * SIG2INV));
        rs[j] = 1.0f / s;
    }
    __syncthreads();

    const float r = rs[j];
    float* ob = out + (size_t)b * NP1 * M + (size_t)i * C + j;

    // ---- Pass 3: recompute exp, normalize, stream out ----
    #pragma unroll 4
    for (int p = p0; p < p1; ++p) {
        float2 xy = pts[p];
        float dy = xy.y - cy;
        float dx = xy.x - cx;
        float d  = fmaf(dx, dx, dy * dy);
        ob[(size_t)p * M] = __expf(fmaf(-d, SIG2INV, qk)) * r;
    }
    // Background row (p = NPT), one wave's worth of threads.
    if (t < C) {
        ob[(size_t)NPT * M] = __expf(fmaf(-bgs[j], SIG2INV, qk)) * r;
    }
}

extern "C" void kernel_launch(void* const* d_in, const int* in_sizes, int n_in,
                              void* d_out, int out_size, void* d_ws, size_t ws_size,
                              hipStream_t stream) {
    const float* points = (const float*)d_in[0];   // [16, 512, 2] fp32
    const float* st     = (const float*)d_in[1];   // [16] fp32
    float* out          = (float*)d_out;           // [16, 513, 4096] fp32

    const int B = in_sizes[1];                     // 16 images
    dim3 grid(B * C);                              // 1024 blocks (b*64 + i)
    dim3 block(256);
    pp_kernel<<<grid, block, 0, stream>>>(points, st, out);
}

// Round 2
// 141.066 us; speedup vs baseline: 1.0463x; 1.0463x over previous
//
#include <hip/hip_runtime.h>
#include <hip/hip_bf16.h>
#include <cstddef>

// B=16, N=512, C_SIZE=512, STRIDE=8 -> C=64, M=4096, out [16, 513, 4096] fp32.
constexpr int NPT = 512;
constexpr int C   = 64;
constexpr int M   = C * C;
constexpr int NP1 = NPT + 1;
constexpr float K = 1.0f / 128.0f;     // 1/(2*sigma^2)
constexpr float BG_RATIO = 0.15f;
constexpr float EPS = 1e-5f;

// Block = 256 threads = 4 waves per (b, i) grid row.
// Thread t: jg = t&15 -> owns pixels j = 4*jg..4*jg+3 (float4 stores);
//           pc = t>>4 -> owns points [32*pc, 32*pc+32).
// No max-shift needed: logits <= 0 and the bg term bounds the softmax
// denominator below by exp(-76.8/128) ~= 0.55 (min(mind,bg) <= s*BG_RATIO*... <= 76.8^2/...),
// so min & exp-sum fuse into ONE loop over points; a second loop normalizes+stores.
__global__ __launch_bounds__(256) void pp_kernel(
    const float* __restrict__ points,   // [B, NPT, 2] (x, y)
    const float* __restrict__ st,       // [B]
    float* __restrict__ out)            // [B, NP1, M]
{
    const int b    = blockIdx.x >> 6;
    const int i    = blockIdx.x & 63;
    const int t    = threadIdx.x;
    const int lane = t & 63;
    const int w    = t >> 6;
    const int jg   = t & 15;
    const int pc   = t >> 4;

    const float cy  = (float)(i * 8 + 4);
    const float cx0 = (float)(jg * 32 + 4);   // j = 4*jg   -> x center
    const float cx1 = cx0 + 8.0f;
    const float cx2 = cx0 + 16.0f;
    const float cx3 = cx0 + 24.0f;

    __shared__ float2 pts[NPT];          // 4 KB
    __shared__ float4 redmin[4][16];     // 1 KB  [wave][jg]
    __shared__ float4 redsum[4][16];     // 1 KB
    __shared__ float  rs[C];             // 1/denominator per pixel
    __shared__ float  bgs[C];            // bg distance per pixel

    const float2* pb = (const float2*)(points + (size_t)b * NPT * 2);
    for (int p = t; p < NPT; p += 256) pts[p] = pb[p];
    __syncthreads();

    const int p0 = pc * 32;

    // ---- Fused pass: min distance AND sum of exp over this chunk ----
    float4 mn = make_float4(3.4e38f, 3.4e38f, 3.4e38f, 3.4e38f);
    float4 sm = make_float4(0.f, 0.f, 0.f, 0.f);
    #pragma unroll 4
    for (int k = 0; k < 32; ++k) {
        float2 xy = pts[p0 + k];
        float dy  = xy.y - cy;
        float dy2 = dy * dy;
        float dx0 = xy.x - cx0, dx1 = xy.x - cx1, dx2 = xy.x - cx2, dx3 = xy.x - cx3;
        float d0 = fmaf(dx0, dx0, dy2);
        float d1 = fmaf(dx1, dx1, dy2);
        float d2 = fmaf(dx2, dx2, dy2);
        float d3 = fmaf(dx3, dx3, dy2);
        mn.x = fminf(mn.x, d0); mn.y = fminf(mn.y, d1);
        mn.z = fminf(mn.z, d2); mn.w = fminf(mn.w, d3);
        sm.x += __expf(-d0 * K); sm.y += __expf(-d1 * K);
        sm.z += __expf(-d2 * K); sm.w += __expf(-d3 * K);
    }

    // Reduce over the 4 chunks resident in this wave (lane bits 4,5).
    #pragma unroll
    for (int off = 16; off <= 32; off <<= 1) {
        mn.x = fminf(mn.x, __shfl_xor(mn.x, off));
        mn.y = fminf(mn.y, __shfl_xor(mn.y, off));
        mn.z = fminf(mn.z, __shfl_xor(mn.z, off));
        mn.w = fminf(mn.w, __shfl_xor(mn.w, off));
        sm.x += __shfl_xor(sm.x, off);
        sm.y += __shfl_xor(sm.y, off);
        sm.z += __shfl_xor(sm.z, off);
        sm.w += __shfl_xor(sm.w, off);
    }
    if (lane < 16) { redmin[w][lane] = mn; redsum[w][lane] = sm; }
    __syncthreads();

    // Final cross-wave reduce + bg + reciprocal denominator (64 threads).
    if (t < C) {
        const float* rm = (const float*)redmin;   // [4][64] words
        const float* rq = (const float*)redsum;
        float m0 = fminf(fminf(rm[t], rm[64 + t]), fminf(rm[128 + t], rm[192 + t]));
        float s0 = (rq[t] + rq[64 + t]) + (rq[128 + t] + rq[192 + t]);
        float ss = st[b] * BG_RATIO;
        float bg = (ss * ss) / (m0 + EPS);
        float tot = s0 + __expf(-bg * K);
        bgs[t] = bg;
        rs[t]  = 1.0f / tot;
    }
    __syncthreads();

    const float4 r4 = *(const float4*)&rs[jg * 4];

    // ---- Store pass: recompute exp, normalize, float4 stream out ----
    float* ob = out + (size_t)b * NP1 * M + (size_t)p0 * M + i * C + jg * 4;
    #pragma unroll 4
    for (int k = 0; k < 32; ++k) {
        float2 xy = pts[p0 + k];
        float dy  = xy.y - cy;
        float dy2 = dy * dy;
        float dx0 = xy.x - cx0, dx1 = xy.x - cx1, dx2 = xy.x - cx2, dx3 = xy.x - cx3;
        float4 v;
        v.x = __expf(-fmaf(dx0, dx0, dy2) * K) * r4.x;
        v.y = __expf(-fmaf(dx1, dx1, dy2) * K) * r4.y;
        v.z = __expf(-fmaf(dx2, dx2, dy2) * K) * r4.z;
        v.w = __expf(-fmaf(dx3, dx3, dy2) * K) * r4.w;
        *(float4*)(ob + (size_t)k * M) = v;
    }

    // Background row (p = NPT): 64 consecutive floats per block.
    if (t < C) {
        out[(size_t)b * NP1 * M + (size_t)NPT * M + i * C + t] =
            __expf(-bgs[t] * K) * rs[t];
    }
}

extern "C" void kernel_launch(void* const* d_in, const int* in_sizes, int n_in,
                              void* d_out, int out_size, void* d_ws, size_t ws_size,
                              hipStream_t stream) {
    const float* points = (const float*)d_in[0];   // [16, 512, 2] fp32
    const float* st     = (const float*)d_in[1];   // [16] fp32
    float* out          = (float*)d_out;           // [16, 513, 4096] fp32

    const int B = in_sizes[1];                     // 16
    dim3 grid(B * C);                              // 1024 blocks: (b*64 + i)
    dim3 block(256);
    pp_kernel<<<grid, block, 0, stream>>>(points, st, out);
}